// Round 12
// baseline (395.671 us; speedup 1.0000x reference)
//
#include <hip/hip_runtime.h>
#include <hip/hip_bf16.h>
#include <math.h>

// Problem constants (reference: B=64, L=1024, H=64, VOCAB=64)
#define BB 64
#define LL 1024
#define HH 64

typedef float v4f __attribute__((ext_vector_type(4)));
#define F4 __builtin_elementwise_fma

// ---------------------------------------------------------------------------
// Kernel 1: per-token phase (v1, best measured).
// ---------------------------------------------------------------------------
__global__ __launch_bounds__(256, 1)
void token_kernel(const int* __restrict__ seq,
                  const float* __restrict__ embed_W,
                  const float* __restrict__ ff_W1, const float* __restrict__ ff_b1,
                  const float* __restrict__ ff_W2, const float* __restrict__ ff_b2,
                  const float* __restrict__ ln_g, const float* __restrict__ ln_b,
                  const float* __restrict__ kp_W, const float* __restrict__ vp_W,
                  const float* __restrict__ qp_W,
                  float* __restrict__ knv, float* __restrict__ vthr,
                  float* __restrict__ qbuf)
{
    __shared__ __align__(16) float h_s[32][64];    // 8 KB
    __shared__ __align__(16) float t1_s[32][128];  // 16 KB
    __shared__ __align__(16) float hn_s[32][64];   // 8 KB

    const int tid  = threadIdx.x;
    const int tok0 = blockIdx.x * 32;

    // ---- Stage A: embedding gather into LDS ----
#pragma unroll
    for (int k = 0; k < 8; ++k) {
        int e   = k * 256 + tid;
        int tok = e >> 6, i = e & 63;
        int s   = seq[tok0 + tok];
        h_s[tok][i] = embed_W[s * 64 + i];
    }
    __syncthreads();

    // ---- Stage B: FF1 (64 -> 128, ReLU) ----
    {
        const int j = tid & 127;
        const int g = tid >> 7;
        float w1c[64];
#pragma unroll
        for (int ii = 0; ii < 64; ++ii) w1c[ii] = ff_W1[ii * 128 + j];
        const float b1j = ff_b1[j];
#pragma unroll
        for (int tk = 0; tk < 16; ++tk) {
            const int tok = g * 16 + tk;
            const float4* h4 = (const float4*)h_s[tok];
            float a0 = b1j, a1 = 0.f, a2 = 0.f, a3 = 0.f;
#pragma unroll
            for (int w = 0; w < 16; ++w) {
                float4 hv = h4[w];
                a0 = fmaf(hv.x, w1c[4*w+0], a0);
                a1 = fmaf(hv.y, w1c[4*w+1], a1);
                a2 = fmaf(hv.z, w1c[4*w+2], a2);
                a3 = fmaf(hv.w, w1c[4*w+3], a3);
            }
            t1_s[tok][j] = fmaxf((a0 + a1) + (a2 + a3), 0.f);
        }
    }
    __syncthreads();

    // ---- Stage C: FF2 (128 -> 64) + residual + LayerNorm ----
    {
        const int i  = tid & 63;
        const int w4 = tid >> 6;
        const float b2i = ff_b2[i];
        const float gi  = ln_g[i];
        const float bi  = ln_b[i];
        float accf[8];
#pragma unroll
        for (int tk = 0; tk < 8; ++tk) accf[tk] = b2i;
#pragma unroll
        for (int h = 0; h < 2; ++h) {
            float w2c[64];
#pragma unroll
            for (int jj = 0; jj < 64; ++jj) w2c[jj] = ff_W2[(h*64 + jj) * 64 + i];
#pragma unroll
            for (int tk = 0; tk < 8; ++tk) {
                const int tok = w4 * 8 + tk;
                const float4* t4 = (const float4*)&t1_s[tok][h*64];
                float a0 = 0.f, a1 = 0.f, a2 = 0.f, a3 = 0.f;
#pragma unroll
                for (int w = 0; w < 16; ++w) {
                    float4 tv = t4[w];
                    a0 = fmaf(tv.x, w2c[4*w+0], a0);
                    a1 = fmaf(tv.y, w2c[4*w+1], a1);
                    a2 = fmaf(tv.z, w2c[4*w+2], a2);
                    a3 = fmaf(tv.w, w2c[4*w+3], a3);
                }
                accf[tk] += (a0 + a1) + (a2 + a3);
            }
        }
#pragma unroll
        for (int tk = 0; tk < 8; ++tk) {
            const int tok = w4 * 8 + tk;
            float x = h_s[tok][i] + accf[tk];
            float s = x;
#pragma unroll
            for (int m = 32; m > 0; m >>= 1) s += __shfl_xor(s, m);
            float mu = s * (1.f / 64.f);
            float d  = x - mu;
            float s2 = d * d;
#pragma unroll
            for (int m = 32; m > 0; m >>= 1) s2 += __shfl_xor(s2, m);
            float var = s2 * (1.f / 64.f);
            hn_s[tok][i] = d / sqrtf(var + 1e-5f) * gi + bi;
        }
    }
    __syncthreads();

    // ---- Stage D: kn/v into packed stream (t<1023) OR q (t==1023) ----
    {
        const int i  = tid & 63;
        const int w4 = tid >> 6;
        float kc[64], vc[64];
#pragma unroll
        for (int ii = 0; ii < 64; ++ii) {
            kc[ii] = kp_W[ii * 64 + i];
            vc[ii] = vp_W[ii * 64 + i];
        }
#pragma unroll
        for (int tk = 0; tk < 8; ++tk) {
            const int tok = w4 * 8 + tk;
            const int tg  = tok0 + tok;
            const int b   = tg >> 10;
            const int t   = tg & 1023;
            const float4* hn4 = (const float4*)hn_s[tok];
            if (t < 1023) {
                float ka0=0.f,ka1=0.f,ka2=0.f,ka3=0.f;
                float va0=0.f,va1=0.f,va2=0.f,va3=0.f;
#pragma unroll
                for (int w = 0; w < 16; ++w) {
                    float4 hv = hn4[w];
                    ka0 = fmaf(hv.x, kc[4*w+0], ka0);
                    ka1 = fmaf(hv.y, kc[4*w+1], ka1);
                    ka2 = fmaf(hv.z, kc[4*w+2], ka2);
                    ka3 = fmaf(hv.w, kc[4*w+3], ka3);
                    va0 = fmaf(hv.x, vc[4*w+0], va0);
                    va1 = fmaf(hv.y, vc[4*w+1], va1);
                    va2 = fmaf(hv.z, vc[4*w+2], va2);
                    va3 = fmaf(hv.w, vc[4*w+3], va3);
                }
                float ka = (ka0 + ka1) + (ka2 + ka3);
                float va = (va0 + va1) + (va2 + va3);
                float kn2 = ka * ka, vn2 = va * va;
#pragma unroll
                for (int m = 32; m > 0; m >>= 1) {
                    kn2 += __shfl_xor(kn2, m);
                    vn2 += __shfl_xor(vn2, m);
                }
                float knorm = fmaxf(sqrtf(kn2), 1e-12f);
                size_t row = ((size_t)b * 1024 + t) * 128;
                knv[row + i]      = ka / knorm;
                knv[row + 64 + i] = va;
                if (i == 0) vthr[b * 1024 + t] = 0.16f * vn2;   // SQUARED threshold
            } else {
                float qa0=0.f,qa1=0.f,qa2=0.f,qa3=0.f;
#pragma unroll
                for (int w = 0; w < 16; ++w) {
                    float4 hv = hn4[w];
                    qa0 = fmaf(hv.x, qp_W[(4*w+0)*64 + i], qa0);
                    qa1 = fmaf(hv.y, qp_W[(4*w+1)*64 + i], qa1);
                    qa2 = fmaf(hv.z, qp_W[(4*w+2)*64 + i], qa2);
                    qa3 = fmaf(hv.w, qp_W[(4*w+3)*64 + i], qa3);
                }
                qbuf[b * 64 + i] = (qa0 + qa1) + (qa2 + qa3);
            }
        }
    }
}

// ---------------------------------------------------------------------------
// Kernel 2: sequential fast-weight scan + output head.
// LAG-1 STALE EXCHANGE on the r8 G=2 / 4-wave structure.
//
// Chunk u (steps 2u,2u+1):
//   1. read pex[PAR^1]: partials of base_stale_i = M_{u-2}.kn_{2u+i}
//      (published by chunk u-1, visible since its barrier) -- issued at the
//      chunk TOP so its LDS latency hides under UPD/load issue.
//   2. UPD with gates(u-1) on rows 2u-2,2u-1 (bank P)  -> M = M_{u-1}
//   3. reload bank P <- rows 2u+2,2u+3; peek their per-lane scalars
//   4. EXACT correction: vp_i = base_stale_i + Ga_i*gdp + Gb_i*gdq
//      (Ga_i = kn_{2u-2}.kn_{2u+i}, Gb_i = kn_{2u-1}.kn_{2u+i} -- the
//      Gram terms of the two updates applied since the stale dot; reduced
//      one chunk ahead, gate-independent)
//   5. one wsum8 batch: 3 d-products + {4 cross Grams + 1 within Gram} for
//      chunk u+1; gate algebra identical to r8 (pair expansion e1)
//   6. DOT of M_{u-1} with the freshly loaded rows 2u+2,2u+3; publish to
//      pex[PAR] (read by chunk u+1)
//   7. lgkmcnt(0) + s_barrier
// The publish->read round-trip is OFF the gate-serial path: reads are of
// chunk-old data. All gate inputs remain bit-identical across the 4 waves
// (fixed trees, redundant reduces).
// ---------------------------------------------------------------------------

template<int CTRL>
__device__ __forceinline__ float dppadd(float x) {
    int y = __builtin_amdgcn_update_dpp(0, __float_as_int(x), CTRL, 0xF, 0xF, true);
    return x + __int_as_float(y);
}

__device__ __forceinline__ float bcast63(float x) {
    return __int_as_float(__builtin_amdgcn_readlane(__float_as_int(x), 63));
}

// full-wave (64 lane) sum, result broadcast (prologue use)
__device__ __forceinline__ float wave_sum64(float x) {
    x = dppadd<0x111>(x); x = dppadd<0x112>(x);
    x = dppadd<0x114>(x); x = dppadd<0x118>(x);
    x = dppadd<0x142>(x); x = dppadd<0x143>(x);
    return bcast63(x);
}

// eight independent wave sums, DPP levels interleaved (latency amortized)
__device__ __forceinline__ void wsum8(float& a, float& b, float& c, float& d,
                                      float& e, float& f, float& g, float& h) {
#define LVL(C) a=dppadd<C>(a); b=dppadd<C>(b); c=dppadd<C>(c); d=dppadd<C>(d); \
               e=dppadd<C>(e); f=dppadd<C>(f); g=dppadd<C>(g); h=dppadd<C>(h);
    LVL(0x111) LVL(0x112) LVL(0x114) LVL(0x118) LVL(0x142) LVL(0x143)
#undef LVL
    a=bcast63(a); b=bcast63(b); c=bcast63(c); d=bcast63(d);
    e=bcast63(e); f=bcast63(f); g=bcast63(g); h=bcast63(h);
}

// load this wave's quarter of a kn row into quarter-set P (4 x ds_read_b128)
#define LOADK4(P, ROW) do { \
    const float* r_ = (ROW) + (wid << 4); \
    P##0 = *(const v4f*)(r_ + 0);  P##1 = *(const v4f*)(r_ + 4); \
    P##2 = *(const v4f*)(r_ + 8);  P##3 = *(const v4f*)(r_ + 12); \
} while (0)

// M(quarter) += G * P(quarter)   (branchless; G==0 exact no-op on finite P)
#define UPD4(P, G) do { \
    v4f gv_ = {G, G, G, G}; \
    m0 = F4(gv_, P##0, m0); m1 = F4(gv_, P##1, m1); \
    m2 = F4(gv_, P##2, m2); m3 = F4(gv_, P##3, m3); \
} while (0)

// One lag-1 chunk u (steps 2u, 2u+1). Bank P0_,P1_ = rows 2u-2,2u-1 at entry
// (UPD sources), reloaded with rows 2u+2,2u+3 (ROW2/ROW3) and DOT'd.
// Carried: gdp,gdq = gates(u-1); knl0,knl1/vv0,vv1/th0,th1 = rows 2u,2u+1
// scalars; Ga0,Gb0,Ga1,Gb1 = cross Grams (2u-2,2u-1)x(2u,2u+1); c01 =
// kn_{2u}.kn_{2u+1}. PAR = u&1: read pex[PAR^1], write pex[PAR].
#define CHUNK2L(P0_, P1_, ROW2, ROW3, TH2P, TH3P, PAR) do { \
    float2 p0_ = ((const float2*)pex[(PAR)^1][0])[lane]; \
    float2 p1_ = ((const float2*)pex[(PAR)^1][1])[lane]; \
    float2 p2_ = ((const float2*)pex[(PAR)^1][2])[lane]; \
    float2 p3_ = ((const float2*)pex[(PAR)^1][3])[lane]; \
    UPD4(P0_, gdp); \
    UPD4(P1_, gdq); \
    LOADK4(P0_, ROW2); \
    LOADK4(P1_, ROW3); \
    float knl2_ = (ROW2)[lane]; \
    float knl3_ = (ROW3)[lane]; \
    float vv2_  = (ROW2)[64 + lane]; \
    float vv3_  = (ROW3)[64 + lane]; \
    float th2_  = *(TH2P); \
    float th3_  = *(TH3P); \
    float base0_ = (p0_.x + p1_.x) + (p2_.x + p3_.x); \
    float base1_ = (p0_.y + p1_.y) + (p2_.y + p3_.y); \
    float vp0_ = fmaf(Gb0, gdq, fmaf(Ga0, gdp, base0_)); \
    float vp1_ = fmaf(Gb1, gdq, fmaf(Ga1, gdp, base1_)); \
    float d00_ = vv0 - vp0_; \
    float d01_ = vv1 - vp1_; \
    float x0_ = d00_ * d00_, x1_ = d00_ * d01_, x2_ = d01_ * d01_; \
    float y0_ = knl0 * knl2_, y1_ = knl1 * knl2_; \
    float y2_ = knl0 * knl3_, y3_ = knl1 * knl3_, y4_ = knl2_ * knl3_; \
    wsum8(x0_, x1_, x2_, y0_, y1_, y2_, y3_, y4_); \
    bool g0_ = x0_ > th0; \
    float corr_ = fmaf(2.f * c01, x1_, -(c01 * c01) * x0_); \
    float e1_ = g0_ ? (x2_ - corr_) : x2_; \
    bool g1_ = e1_ > th1; \
    float gd0_ = g0_ ? d00_ : 0.f; \
    float d1_  = fmaf(-c01, gd0_, d01_); \
    gdp = gd0_; \
    gdq = g1_ ? d1_ : 0.f; \
    v4f q_ = F4(m0, P0_##0, F4(m1, P0_##1, F4(m2, P0_##2, m3 * P0_##3))); \
    float own0_ = (q_.x + q_.y) + (q_.z + q_.w); \
    v4f r_ = F4(m0, P1_##0, F4(m1, P1_##1, F4(m2, P1_##2, m3 * P1_##3))); \
    float own1_ = (r_.x + r_.y) + (r_.z + r_.w); \
    ((float2*)pex[PAR][wid])[lane] = make_float2(own0_, own1_); \
    knl0 = knl2_; knl1 = knl3_; vv0 = vv2_; vv1 = vv3_; th0 = th2_; th1 = th3_; \
    Ga0 = y0_; Gb0 = y1_; Ga1 = y2_; Gb1 = y3_; c01 = y4_; \
    asm volatile("s_waitcnt lgkmcnt(0)\n\ts_barrier" ::: "memory"); \
} while (0)

// 8 chunks covering one 16-row buffer (steps 16c .. 16c+15).
// Bank parity: even chunks use (U,V), odd chunks (S,T) -- a bank is loaded
// at chunk u (rows 2u+2,2u+3), idle at u+1, UPD'd+reloaded at u+2.
#define BUF8L(CB, NB, TP) \
    CHUNK2L(U,V,(CB)+2*128, (CB)+3*128, (TP)+2, (TP)+3, 0); \
    CHUNK2L(S,T,(CB)+4*128, (CB)+5*128, (TP)+4, (TP)+5, 1); \
    CHUNK2L(U,V,(CB)+6*128, (CB)+7*128, (TP)+6, (TP)+7, 0); \
    CHUNK2L(S,T,(CB)+8*128, (CB)+9*128, (TP)+8, (TP)+9, 1); \
    CHUNK2L(U,V,(CB)+10*128,(CB)+11*128,(TP)+10,(TP)+11,0); \
    CHUNK2L(S,T,(CB)+12*128,(CB)+13*128,(TP)+12,(TP)+13,1); \
    CHUNK2L(U,V,(CB)+14*128,(CB)+15*128,(TP)+14,(TP)+15,0); \
    CHUNK2L(S,T,(NB)+0*128, (NB)+1*128, (TP)+16,(TP)+17,1);

// async copy: 1024 B contiguous global -> contiguous LDS (one inst)
__device__ __forceinline__ void gl2lds_1k(const float* g, float* l, int lane) {
    __builtin_amdgcn_global_load_lds(
        (const __attribute__((address_space(1))) void*)(g + lane * 4),
        (__attribute__((address_space(3))) void*)l, 16, 0, 0);
}

// wave w stages rows 4w..4w+3 of a 16-row buffer (2 KB = 2 insts)
__device__ __forceinline__ void prefetch_quarter(const float* g, float* l,
                                                 int lane, int wid) {
#pragma unroll
    for (int j = 0; j < 2; ++j)
        gl2lds_1k(g + wid * 512 + j * 256, l + wid * 512 + j * 256, lane);
}

__global__ __launch_bounds__(256, 1)
void scan_kernel(const float* __restrict__ knv,
                 const float* __restrict__ vthr,
                 const float* __restrict__ qbuf,
                 const float* __restrict__ rp_W, const float* __restrict__ rp_b,
                 const float* __restrict__ out_W, const float* __restrict__ out_b,
                 float* __restrict__ out)
{
    const int b    = blockIdx.x;
    const int tid  = threadIdx.x;
    const int lane = tid & 63;
    const int wid  = tid >> 6;
    const float* knvb = knv  + (size_t)b * 1024 * 128;
    const float* thrb = vthr + (size_t)b * 1024;

    __shared__ __align__(16) float thr_s[1040];      // th^2 per step
    __shared__ __align__(16) float buf[3 * 2048];    // 3 x 8 KB buffers
    __shared__ __align__(16) float pex[2][4][128];   // [parity][wave][lane*2]
    __shared__ float sh[64];

    // M quarter: columns [16*wid, 16*wid+16) of lane's row (4 v4f)
    v4f m0={0,0,0,0}, m1={0,0,0,0}, m2={0,0,0,0}, m3={0,0,0,0};
    // two row banks (2 rows each); parity-alternating lifecycle
    v4f S0,S1,S2,S3;
    v4f T0,T1,T2,T3;
    v4f U0,U1,U2,U3;
    v4f V0,V1,V2,V3;

    // staging: wave 0 also loads thr (4 insts); each wave 2 insts/buffer
    if (wid == 0) {
#pragma unroll
        for (int w = 0; w < 4; ++w) gl2lds_1k(thrb + w * 256, thr_s + w * 256, lane);
    }
    prefetch_quarter(knvb,        buf,        lane, wid);
    prefetch_quarter(knvb + 2048, buf + 2048, lane, wid);
    prefetch_quarter(knvb + 4096, buf + 4096, lane, wid);

    // zero pex (both parities): 1024 floats / 256 threads = 1 float4 each
    {
        float4 z4 = make_float4(0.f, 0.f, 0.f, 0.f);
        ((float4*)pex)[tid] = z4;
    }

    // thr + buffers 0,1 resident own-wave (buffer 2 = 2 insts in flight);
    // barrier makes all waves' quarters + pex zeros visible.
    asm volatile("s_waitcnt vmcnt(2) lgkmcnt(0)\n\ts_barrier" ::: "memory");

    // prologue: chunk 0 (par 0) UPDs bank U,V as rows -2,-1 -> zero them;
    // bank S,T <- rows 0,1 (UPD'd at chunk 1 with gates(0)).
    LOADK4(S, buf);
    LOADK4(T, buf + 128);
    {
        v4f z_ = {0.f, 0.f, 0.f, 0.f};
        U0=z_;U1=z_;U2=z_;U3=z_;
        V0=z_;V1=z_;V2=z_;V3=z_;
    }
    float knl0 = buf[lane];              // kn_0[lane]
    float knl1 = buf[128 + lane];        // kn_1[lane]
    float vv0  = buf[64 + lane];         // v_0[lane]
    float vv1  = buf[192 + lane];        // v_1[lane]
    float th0  = thr_s[0];
    float th1  = thr_s[1];
    float c01  = wave_sum64(knl0 * knl1);   // kn_0 . kn_1
    float Ga0 = 0.f, Gb0 = 0.f, Ga1 = 0.f, Gb1 = 0.f;  // x gdp=gdq=0
    float gdp = 0.f, gdq = 0.f;

#pragma unroll 1
    for (int c = 0; c < 62; ++c) {
        // own outstanding <= 4 (buffers c+1, c+2); vmcnt(2) -> buffer c+1
        // resident own-wave; chunk barriers give cross-wave visibility.
        asm volatile("s_waitcnt vmcnt(2)" ::: "memory");
        const float* cb = buf + (c % 3) * 2048;
        const float* nb = buf + ((c + 1) % 3) * 2048;
        const float* tp = thr_s + c * 16;
        BUF8L(cb, nb, tp)
        if (c <= 60)
            prefetch_quarter(knvb + (size_t)(c + 3) * 2048,
                             buf + (c % 3) * 2048, lane, wid);
    }
    asm volatile("s_waitcnt vmcnt(0)" ::: "memory");
    asm volatile("s_barrier" ::: "memory");   // all waves' buffers 62,63 staged
    {   // buffer 62 (slot 2), lookahead into buffer 63 (slot 0)
        const float* cb = buf + 2 * 2048;
        const float* nb = buf;
        const float* tp = thr_s + 62 * 16;
        BUF8L(cb, nb, tp)
    }
    {   // buffer 63 (slot 0): steps 1008..1023 (1023 = dummy); NB dummy slot 1
        const float* cb = buf;
        const float* nb = buf + 2048;
        const float* tp = thr_s + 63 * 16;
        BUF8L(cb, nb, tp)
    }
    // final update: M_{1022} = M_{1021} + gd_{1022} kn_{1022}^T
    // (gdp = gd_{1022}; U,V hold rows 1022,1023: loaded at chunk 510)
    UPD4(U, gdp);

    // ---- output head: vq = M q (quarter + exchange), wave 0 finishes ----
    {
        const v4f* qq = (const v4f*)(qbuf + b * 64);
        const int w4i = 4 * wid;
        v4f aq = F4(m0, qq[w4i+0], F4(m1, qq[w4i+1],
                 F4(m2, qq[w4i+2],  m3 * qq[w4i+3])));
        float vq_own = (aq.x + aq.y) + (aq.z + aq.w);
        pex[0][wid][lane] = vq_own;
        asm volatile("s_waitcnt lgkmcnt(0)\n\ts_barrier" ::: "memory");

        if (wid == 0) {
            float vq = (pex[0][0][lane] + pex[0][1][lane])
                     + (pex[0][2][lane] + pex[0][3][lane]);
            sh[lane] = vq;
            asm volatile("s_waitcnt lgkmcnt(0)" ::: "memory");
            float r = rp_b[lane];
#pragma unroll
            for (int ii = 0; ii < 64; ++ii) r = fmaf(sh[ii], rp_W[ii * 64 + lane], r);
            asm volatile("s_waitcnt lgkmcnt(0)" ::: "memory");
            sh[lane] = r;
            asm volatile("s_waitcnt lgkmcnt(0)" ::: "memory");
            float o = out_b[lane];
#pragma unroll
            for (int ii = 0; ii < 64; ++ii) o = fmaf(sh[ii], out_W[ii * 64 + lane], o);
            out[b * 64 + lane] = o;
        }
    }
}

// ---------------------------------------------------------------------------
// Launch. Workspace (fp32): knv[64][1024][128] (33.55 MB, t=1023 row unused) |
// vthr[64][1024] (262 KB) | qbuf[64][64]. Total ~33.9 MB.
// ---------------------------------------------------------------------------
extern "C" void kernel_launch(void* const* d_in, const int* in_sizes, int n_in,
                              void* d_out, int out_size, void* d_ws, size_t ws_size,
                              hipStream_t stream)
{
    const int*   seq   = (const int*)  d_in[0];
    const float* embed = (const float*)d_in[1];
    const float* ffW1  = (const float*)d_in[2];
    const float* ffb1  = (const float*)d_in[3];
    const float* ffW2  = (const float*)d_in[4];
    const float* ffb2  = (const float*)d_in[5];
    const float* lng   = (const float*)d_in[6];
    const float* lnb   = (const float*)d_in[7];
    const float* kpW   = (const float*)d_in[8];
    const float* vpW   = (const float*)d_in[9];
    const float* qpW   = (const float*)d_in[10];
    const float* rpW   = (const float*)d_in[11];
    const float* rpb   = (const float*)d_in[12];
    const float* outW  = (const float*)d_in[13];
    const float* outb  = (const float*)d_in[14];
    float* out = (float*)d_out;

    float* knv  = (float*)d_ws;
    float* vthr = knv  + (size_t)64 * 1024 * 128;
    float* qbuf = vthr + (size_t)64 * 1024;

    token_kernel<<<2048, 256, 0, stream>>>(seq, embed, ffW1, ffb1, ffW2, ffb2,
                                           lng, lnb, kpW, vpW, qpW,
                                           knv, vthr, qbuf);
    scan_kernel<<<64, 256, 0, stream>>>(knv, vthr, qbuf,
                                        rpW, rpb, outW, outb, out);
}

// Round 13
// 387.877 us; speedup vs baseline: 1.0201x; 1.0201x over previous
//
#include <hip/hip_runtime.h>
#include <hip/hip_bf16.h>
#include <math.h>

// Problem constants (reference: B=64, L=1024, H=64, VOCAB=64)
#define BB 64
#define LL 1024
#define HH 64

typedef float v4f __attribute__((ext_vector_type(4)));
#define F4 __builtin_elementwise_fma

// Per-(batch, 32-token-chunk) produced flags. Zeroed per launch via
// hipMemsetAsync on the capture stream (device global avoids ws_size risk).
__device__ int g_flags[2048];   // [b][tc], tc in [0,32)

// ---------------------------------------------------------------------------
// FUSED kernel: blocks 0..63 = per-batch scan (consumers, dispatched FIRST so
// they hold at most 64 of ~1024 resident slots -> no deadlock possible);
// blocks 64..2111 = token work (producers), CHUNK-MAJOR order: block
// 64 + tc*64 + b computes tokens [b*1024 + tc*32, +32) and release-stores
// g_flags[b*32+tc]. Consumers acquire-spin per buffer before prefetching.
// Values are deterministic per launch, so any cross-replay cache staleness
// returns identical data (benign).
// LDS: one 32 KB pool, token uses 8192 floats, scan uses 7232.
// ---------------------------------------------------------------------------

template<int CTRL>
__device__ __forceinline__ float dppadd(float x) {
    int y = __builtin_amdgcn_update_dpp(0, __float_as_int(x), CTRL, 0xF, 0xF, true);
    return x + __int_as_float(y);
}

__device__ __forceinline__ float bcast63(float x) {
    return __int_as_float(__builtin_amdgcn_readlane(__float_as_int(x), 63));
}

__device__ __forceinline__ float wave_sum64(float x) {
    x = dppadd<0x111>(x); x = dppadd<0x112>(x);
    x = dppadd<0x114>(x); x = dppadd<0x118>(x);
    x = dppadd<0x142>(x); x = dppadd<0x143>(x);
    return bcast63(x);
}

// four independent wave sums, DPP levels interleaved (latency amortized)
__device__ __forceinline__ void wsum4(float& a, float& b, float& c, float& d) {
    a = dppadd<0x111>(a); b = dppadd<0x111>(b); c = dppadd<0x111>(c); d = dppadd<0x111>(d);
    a = dppadd<0x112>(a); b = dppadd<0x112>(b); c = dppadd<0x112>(c); d = dppadd<0x112>(d);
    a = dppadd<0x114>(a); b = dppadd<0x114>(b); c = dppadd<0x114>(c); d = dppadd<0x114>(d);
    a = dppadd<0x118>(a); b = dppadd<0x118>(b); c = dppadd<0x118>(c); d = dppadd<0x118>(d);
    a = dppadd<0x142>(a); b = dppadd<0x142>(b); c = dppadd<0x142>(c); d = dppadd<0x142>(d);
    a = dppadd<0x143>(a); b = dppadd<0x143>(b); c = dppadd<0x143>(c); d = dppadd<0x143>(d);
    a = bcast63(a); b = bcast63(b); c = bcast63(c); d = bcast63(d);
}

// load this wave's quarter of a kn row into quarter-set P (4 x ds_read_b128)
#define LOADK4(P, ROW) do { \
    const float* r_ = (ROW) + (wid << 4); \
    P##0 = *(const v4f*)(r_ + 0);  P##1 = *(const v4f*)(r_ + 4); \
    P##2 = *(const v4f*)(r_ + 8);  P##3 = *(const v4f*)(r_ + 12); \
} while (0)

// M(quarter) += G * P(quarter)   (branchless; G==0 exact no-op on finite P)
#define UPD4(P, G) do { \
    v4f gv_ = {G, G, G, G}; \
    m0 = F4(gv_, P##0, m0); m1 = F4(gv_, P##1, m1); \
    m2 = F4(gv_, P##2, m2); m3 = F4(gv_, P##3, m3); \
} while (0)

// One chunk u (steps 2u, 2u+1). r8-verbatim math; TH pointers are GLOBAL.
#define CHUNK2(UP, UQ, XR, XS, ROW2, ROW3, TH2P, TH3P, PAR) do { \
    UPD4(UP, gdp); \
    UPD4(UQ, gdq); \
    v4f q_ = F4(m0, XR##0, F4(m1, XR##1, F4(m2, XR##2, m3 * XR##3))); \
    float own0_ = (q_.x + q_.y) + (q_.z + q_.w); \
    v4f r_ = F4(m0, XS##0, F4(m1, XS##1, F4(m2, XS##2, m3 * XS##3))); \
    float own1_ = (r_.x + r_.y) + (r_.z + r_.w); \
    ((float2*)pex[PAR][wid])[lane] = make_float2(own0_, own1_); \
    asm volatile("s_waitcnt lgkmcnt(0)\n\ts_barrier" ::: "memory"); \
    float2 p0_ = ((const float2*)pex[PAR][0])[lane]; \
    float2 p1_ = ((const float2*)pex[PAR][1])[lane]; \
    float2 p2_ = ((const float2*)pex[PAR][2])[lane]; \
    float2 p3_ = ((const float2*)pex[PAR][3])[lane]; \
    float knl2_ = (ROW2)[lane]; \
    float knl3_ = (ROW3)[lane]; \
    float vv2_  = (ROW2)[64 + lane]; \
    float vv3_  = (ROW3)[64 + lane]; \
    float th2_  = *(TH2P); \
    float th3_  = *(TH3P); \
    LOADK4(UP, ROW2); \
    LOADK4(UQ, ROW3); \
    float base0_ = (p0_.x + p1_.x) + (p2_.x + p3_.x); \
    float base1_ = (p0_.y + p1_.y) + (p2_.y + p3_.y); \
    float d00_ = vv0 - base0_; \
    float d01_ = vv1 - base1_; \
    float x0_ = d00_ * d00_, x1_ = d00_ * d01_; \
    float x2_ = d01_ * d01_, x3_ = knl2_ * knl3_; \
    wsum4(x0_, x1_, x2_, x3_); \
    bool g0_ = x0_ > th0; \
    float corr_ = fmaf(2.f * c3, x1_, -(c3 * c3) * x0_); \
    float e1_ = g0_ ? (x2_ - corr_) : x2_; \
    bool g1_ = e1_ > th1; \
    float gd0_ = g0_ ? d00_ : 0.f; \
    float d1_  = fmaf(-c3, gd0_, d01_); \
    gdp = gd0_; \
    gdq = g1_ ? d1_ : 0.f; \
    vv0 = vv2_; vv1 = vv3_; th0 = th2_; th1 = th3_; c3 = x3_; \
} while (0)

// 8 chunks covering one 16-row buffer (steps 16c .. 16c+15).
#define BUF8(CB, NB, TP) \
    CHUNK2(U,V,S,T,(CB)+2*128, (CB)+3*128, (TP)+2, (TP)+3, 0); \
    CHUNK2(S,T,U,V,(CB)+4*128, (CB)+5*128, (TP)+4, (TP)+5, 1); \
    CHUNK2(U,V,S,T,(CB)+6*128, (CB)+7*128, (TP)+6, (TP)+7, 0); \
    CHUNK2(S,T,U,V,(CB)+8*128, (CB)+9*128, (TP)+8, (TP)+9, 1); \
    CHUNK2(U,V,S,T,(CB)+10*128,(CB)+11*128,(TP)+10,(TP)+11,0); \
    CHUNK2(S,T,U,V,(CB)+12*128,(CB)+13*128,(TP)+12,(TP)+13,1); \
    CHUNK2(U,V,S,T,(CB)+14*128,(CB)+15*128,(TP)+14,(TP)+15,0); \
    CHUNK2(S,T,U,V,(NB)+0*128, (NB)+1*128, (TP)+16,(TP)+17,1);

// async copy: 1024 B contiguous global -> contiguous LDS (one inst)
__device__ __forceinline__ void gl2lds_1k(const float* g, float* l, int lane) {
    __builtin_amdgcn_global_load_lds(
        (const __attribute__((address_space(1))) void*)(g + lane * 4),
        (__attribute__((address_space(3))) void*)l, 16, 0, 0);
}

// wave w stages rows 4w..4w+3 of a 16-row buffer (2 KB = 2 insts)
__device__ __forceinline__ void prefetch_quarter(const float* g, float* l,
                                                 int lane, int wid) {
#pragma unroll
    for (int j = 0; j < 2; ++j)
        gl2lds_1k(g + wid * 512 + j * 256, l + wid * 512 + j * 256, lane);
}

// acquire-spin until producer flag is set (uniform across the wave)
__device__ __forceinline__ void spin_flag(const int* f) {
    while (__hip_atomic_load(f, __ATOMIC_ACQUIRE, __HIP_MEMORY_SCOPE_AGENT) == 0)
        __builtin_amdgcn_s_sleep(16);
}

// ---------------------------------------------------------------------------
// Token body (v1 math, bit-identical; tok0 parametrized; release flag at end)
// ---------------------------------------------------------------------------
__device__ void token_body(float* smem, int bIdx, int tcIdx,
                           const int* __restrict__ seq,
                           const float* __restrict__ embed_W,
                           const float* __restrict__ ff_W1, const float* __restrict__ ff_b1,
                           const float* __restrict__ ff_W2, const float* __restrict__ ff_b2,
                           const float* __restrict__ ln_g, const float* __restrict__ ln_b,
                           const float* __restrict__ kp_W, const float* __restrict__ vp_W,
                           const float* __restrict__ qp_W,
                           float* __restrict__ knv, float* __restrict__ vthr,
                           float* __restrict__ qbuf)
{
    float (*h_s)[64]   = (float(*)[64])smem;          // 2048 floats
    float (*t1_s)[128] = (float(*)[128])(smem + 2048); // 4096 floats
    float (*hn_s)[64]  = (float(*)[64])(smem + 6144);  // 2048 floats

    const int tid  = threadIdx.x;
    const int tok0 = bIdx * 1024 + tcIdx * 32;

    // ---- Stage A: embedding gather into LDS ----
#pragma unroll
    for (int k = 0; k < 8; ++k) {
        int e   = k * 256 + tid;
        int tok = e >> 6, i = e & 63;
        int s   = seq[tok0 + tok];
        h_s[tok][i] = embed_W[s * 64 + i];
    }
    __syncthreads();

    // ---- Stage B: FF1 (64 -> 128, ReLU) ----
    {
        const int j = tid & 127;
        const int g = tid >> 7;
        float w1c[64];
#pragma unroll
        for (int ii = 0; ii < 64; ++ii) w1c[ii] = ff_W1[ii * 128 + j];
        const float b1j = ff_b1[j];
#pragma unroll
        for (int tk = 0; tk < 16; ++tk) {
            const int tok = g * 16 + tk;
            const float4* h4 = (const float4*)h_s[tok];
            float a0 = b1j, a1 = 0.f, a2 = 0.f, a3 = 0.f;
#pragma unroll
            for (int w = 0; w < 16; ++w) {
                float4 hv = h4[w];
                a0 = fmaf(hv.x, w1c[4*w+0], a0);
                a1 = fmaf(hv.y, w1c[4*w+1], a1);
                a2 = fmaf(hv.z, w1c[4*w+2], a2);
                a3 = fmaf(hv.w, w1c[4*w+3], a3);
            }
            t1_s[tok][j] = fmaxf((a0 + a1) + (a2 + a3), 0.f);
        }
    }
    __syncthreads();

    // ---- Stage C: FF2 (128 -> 64) + residual + LayerNorm ----
    {
        const int i  = tid & 63;
        const int w4 = tid >> 6;
        const float b2i = ff_b2[i];
        const float gi  = ln_g[i];
        const float bi  = ln_b[i];
        float accf[8];
#pragma unroll
        for (int tk = 0; tk < 8; ++tk) accf[tk] = b2i;
#pragma unroll
        for (int h = 0; h < 2; ++h) {
            float w2c[64];
#pragma unroll
            for (int jj = 0; jj < 64; ++jj) w2c[jj] = ff_W2[(h*64 + jj) * 64 + i];
#pragma unroll
            for (int tk = 0; tk < 8; ++tk) {
                const int tok = w4 * 8 + tk;
                const float4* t4 = (const float4*)&t1_s[tok][h*64];
                float a0 = 0.f, a1 = 0.f, a2 = 0.f, a3 = 0.f;
#pragma unroll
                for (int w = 0; w < 16; ++w) {
                    float4 tv = t4[w];
                    a0 = fmaf(tv.x, w2c[4*w+0], a0);
                    a1 = fmaf(tv.y, w2c[4*w+1], a1);
                    a2 = fmaf(tv.z, w2c[4*w+2], a2);
                    a3 = fmaf(tv.w, w2c[4*w+3], a3);
                }
                accf[tk] += (a0 + a1) + (a2 + a3);
            }
        }
#pragma unroll
        for (int tk = 0; tk < 8; ++tk) {
            const int tok = w4 * 8 + tk;
            float x = h_s[tok][i] + accf[tk];
            float s = x;
#pragma unroll
            for (int m = 32; m > 0; m >>= 1) s += __shfl_xor(s, m);
            float mu = s * (1.f / 64.f);
            float d  = x - mu;
            float s2 = d * d;
#pragma unroll
            for (int m = 32; m > 0; m >>= 1) s2 += __shfl_xor(s2, m);
            float var = s2 * (1.f / 64.f);
            hn_s[tok][i] = d / sqrtf(var + 1e-5f) * gi + bi;
        }
    }
    __syncthreads();

    // ---- Stage D: kn/v into packed stream (t<1023) OR q (t==1023) ----
    {
        const int i  = tid & 63;
        const int w4 = tid >> 6;
        float kc[64], vc[64];
#pragma unroll
        for (int ii = 0; ii < 64; ++ii) {
            kc[ii] = kp_W[ii * 64 + i];
            vc[ii] = vp_W[ii * 64 + i];
        }
#pragma unroll
        for (int tk = 0; tk < 8; ++tk) {
            const int tok = w4 * 8 + tk;
            const int tg  = tok0 + tok;
            const int b   = tg >> 10;
            const int t   = tg & 1023;
            const float4* hn4 = (const float4*)hn_s[tok];
            if (t < 1023) {
                float ka0=0.f,ka1=0.f,ka2=0.f,ka3=0.f;
                float va0=0.f,va1=0.f,va2=0.f,va3=0.f;
#pragma unroll
                for (int w = 0; w < 16; ++w) {
                    float4 hv = hn4[w];
                    ka0 = fmaf(hv.x, kc[4*w+0], ka0);
                    ka1 = fmaf(hv.y, kc[4*w+1], ka1);
                    ka2 = fmaf(hv.z, kc[4*w+2], ka2);
                    ka3 = fmaf(hv.w, kc[4*w+3], ka3);
                    va0 = fmaf(hv.x, vc[4*w+0], va0);
                    va1 = fmaf(hv.y, vc[4*w+1], va1);
                    va2 = fmaf(hv.z, vc[4*w+2], va2);
                    va3 = fmaf(hv.w, vc[4*w+3], va3);
                }
                float ka = (ka0 + ka1) + (ka2 + ka3);
                float va = (va0 + va1) + (va2 + va3);
                float kn2 = ka * ka, vn2 = va * va;
#pragma unroll
                for (int m = 32; m > 0; m >>= 1) {
                    kn2 += __shfl_xor(kn2, m);
                    vn2 += __shfl_xor(vn2, m);
                }
                float knorm = fmaxf(sqrtf(kn2), 1e-12f);
                size_t row = ((size_t)b * 1024 + t) * 128;
                knv[row + i]      = ka / knorm;
                knv[row + 64 + i] = va;
                if (i == 0) vthr[b * 1024 + t] = 0.16f * vn2;   // SQUARED threshold
            } else {
                float qa0=0.f,qa1=0.f,qa2=0.f,qa3=0.f;
#pragma unroll
                for (int w = 0; w < 16; ++w) {
                    float4 hv = hn4[w];
                    qa0 = fmaf(hv.x, qp_W[(4*w+0)*64 + i], qa0);
                    qa1 = fmaf(hv.y, qp_W[(4*w+1)*64 + i], qa1);
                    qa2 = fmaf(hv.z, qp_W[(4*w+2)*64 + i], qa2);
                    qa3 = fmaf(hv.w, qp_W[(4*w+3)*64 + i], qa3);
                }
                qbuf[b * 64 + i] = (qa0 + qa1) + (qa2 + qa3);
            }
        }
    }

    // ---- publish: all stores drained by syncthreads, then release flag ----
    __syncthreads();
    if (tid == 0)
        __hip_atomic_store(&g_flags[bIdx * 32 + tcIdx], 1,
                           __ATOMIC_RELEASE, __HIP_MEMORY_SCOPE_AGENT);
}

// ---------------------------------------------------------------------------
// Scan body: r8-verbatim (G=2 chunks, 4-wave column split, 211 µs measured)
// with (a) thr read directly from global (1-chunk lookahead hides latency),
// (b) acquire-spin on g_flags before each buffer prefetch.
// ---------------------------------------------------------------------------
__device__ void scan_body(float* smem, int b,
                          const float* __restrict__ knv,
                          const float* __restrict__ vthr,
                          const float* __restrict__ qbuf,
                          const float* __restrict__ rp_W, const float* __restrict__ rp_b,
                          const float* __restrict__ out_W, const float* __restrict__ out_b,
                          float* __restrict__ out)
{
    const int tid  = threadIdx.x;
    const int lane = tid & 63;
    const int wid  = tid >> 6;
    const float* knvb = knv  + (size_t)b * 1024 * 128;
    const float* thrb = vthr + (size_t)b * 1024;
    const int*   flg  = &g_flags[b * 32];

    float* buf = smem;                                   // 6144 floats (3 x 8KB)
    float (*pex)[4][128] = (float(*)[4][128])(smem + 6144); // [2][4][128]
    float* sh = smem + 7168;                             // 64 floats

    // M quarter: columns [16*wid, 16*wid+16) of lane's row (4 v4f)
    v4f m0={0,0,0,0}, m1={0,0,0,0}, m2={0,0,0,0}, m3={0,0,0,0};
    v4f S0,S1,S2,S3;
    v4f T0,T1,T2,T3;
    v4f U0,U1,U2,U3;
    v4f V0,V1,V2,V3;

    // wait for tcPair 0 (buffers 0,1) and 1 (buffers 2,3), then prefetch
    spin_flag(flg + 0);
    spin_flag(flg + 1);
    prefetch_quarter(knvb,        buf,        lane, wid);
    prefetch_quarter(knvb + 2048, buf + 2048, lane, wid);
    prefetch_quarter(knvb + 4096, buf + 4096, lane, wid);

    // zero pex: 1024 floats / 256 threads = 1 float4 each
    {
        float4 z4 = make_float4(0.f, 0.f, 0.f, 0.f);
        ((float4*)pex)[tid] = z4;
    }

    // buffers 0,1 resident own-wave (buffer 2 = 2 insts in flight)
    asm volatile("s_waitcnt vmcnt(2) lgkmcnt(0)\n\ts_barrier" ::: "memory");

    // prologue: chunk 0 expects S=kn_0, T=kn_1, U=V = kn_{-2,-1} = 0
    LOADK4(S, buf);
    LOADK4(T, buf + 128);
    {
        v4f z_ = {0.f, 0.f, 0.f, 0.f};
        U0=z_;U1=z_;U2=z_;U3=z_;
        V0=z_;V1=z_;V2=z_;V3=z_;
    }
    float vv0 = buf[64 + lane];          // v_0[lane]
    float vv1 = buf[192 + lane];         // v_1[lane]
    float th0 = thrb[0];
    float th1 = thrb[1];
    float c3  = wave_sum64(buf[lane] * buf[128 + lane]);   // kn_0 . kn_1
    float gdp = 0.f, gdq = 0.f;

#pragma unroll 1
    for (int c = 0; c < 62; ++c) {
        asm volatile("s_waitcnt vmcnt(2)" ::: "memory");
        const float* cb = buf + (c % 3) * 2048;
        const float* nb = buf + ((c + 1) % 3) * 2048;
        const float* tp = thrb + c * 16;
        BUF8(cb, nb, tp)
        if (c <= 60) {
            if (((c + 3) & 1) == 0) spin_flag(flg + ((c + 3) >> 1));
            prefetch_quarter(knvb + (size_t)(c + 3) * 2048,
                             buf + (c % 3) * 2048, lane, wid);
        }
    }
    asm volatile("s_waitcnt vmcnt(0)" ::: "memory");
    asm volatile("s_barrier" ::: "memory");   // all waves' buffers 62,63 staged
    {   // buffer 62 (slot 2), lookahead into buffer 63 (slot 0)
        const float* cb = buf + 2 * 2048;
        const float* nb = buf;
        const float* tp = thrb + 62 * 16;
        BUF8(cb, nb, tp)
    }
    {   // buffer 63 (slot 0): steps 1008..1023 (1023 = dummy); NB dummy slot 1
        const float* cb = buf;
        const float* nb = buf + 2048;
        const float* tp = thrb + 63 * 16;
        BUF8(cb, nb, tp)
    }
    // final update: M_{1022} = M_{1021} + gd_{1022} kn_{1022}^T
    UPD4(U, gdp);

    // ---- output head: vq = M q (quarter + exchange), wave 0 finishes ----
    {
        const v4f* qq = (const v4f*)(qbuf + b * 64);
        const int w4i = 4 * wid;
        v4f aq = F4(m0, qq[w4i+0], F4(m1, qq[w4i+1],
                 F4(m2, qq[w4i+2],  m3 * qq[w4i+3])));
        float vq_own = (aq.x + aq.y) + (aq.z + aq.w);
        pex[0][wid][lane] = vq_own;
        asm volatile("s_waitcnt lgkmcnt(0)\n\ts_barrier" ::: "memory");

        if (wid == 0) {
            float vq = (pex[0][0][lane] + pex[0][1][lane])
                     + (pex[0][2][lane] + pex[0][3][lane]);
            sh[lane] = vq;
            asm volatile("s_waitcnt lgkmcnt(0)" ::: "memory");
            float r = rp_b[lane];
#pragma unroll
            for (int ii = 0; ii < 64; ++ii) r = fmaf(sh[ii], rp_W[ii * 64 + lane], r);
            asm volatile("s_waitcnt lgkmcnt(0)" ::: "memory");
            sh[lane] = r;
            asm volatile("s_waitcnt lgkmcnt(0)" ::: "memory");
            float o = out_b[lane];
#pragma unroll
            for (int ii = 0; ii < 64; ++ii) o = fmaf(sh[ii], out_W[ii * 64 + lane], o);
            out[b * 64 + lane] = o;
        }
    }
}

// ---------------------------------------------------------------------------
// Fused kernel. Blocks 0..63: scans. Blocks 64..2111: token chunks
// (chunk-major: block 64 + tc*64 + b -> tokens [b*1024+tc*32, +32)).
// ---------------------------------------------------------------------------
__global__ __launch_bounds__(256, 1)
void fused_kernel(const int* __restrict__ seq,
                  const float* __restrict__ embed_W,
                  const float* __restrict__ ff_W1, const float* __restrict__ ff_b1,
                  const float* __restrict__ ff_W2, const float* __restrict__ ff_b2,
                  const float* __restrict__ ln_g, const float* __restrict__ ln_b,
                  const float* __restrict__ kp_W, const float* __restrict__ vp_W,
                  const float* __restrict__ qp_W,
                  const float* __restrict__ rp_W, const float* __restrict__ rp_b,
                  const float* __restrict__ out_W, const float* __restrict__ out_b,
                  float* __restrict__ knv, float* __restrict__ vthr,
                  float* __restrict__ qbuf, float* __restrict__ out)
{
    __shared__ __align__(16) float smem[8192];   // 32 KB union pool
    const int g = blockIdx.x;
    if (g >= 64) {
        const int tg2 = g - 64;
        const int tc  = tg2 >> 6;
        const int b   = tg2 & 63;
        token_body(smem, b, tc, seq, embed_W, ff_W1, ff_b1, ff_W2, ff_b2,
                   ln_g, ln_b, kp_W, vp_W, qp_W, knv, vthr, qbuf);
    } else {
        scan_body(smem, g, knv, vthr, qbuf, rp_W, rp_b, out_W, out_b, out);
    }
}

// ---------------------------------------------------------------------------
// Launch. Workspace (fp32): knv[64][1024][128] (33.55 MB, t=1023 row unused) |
// vthr[64][1024] (262 KB) | qbuf[64][64]. Flags live in __device__ g_flags,
// zeroed per launch via hipMemsetAsync (capture-safe).
// ---------------------------------------------------------------------------
extern "C" void kernel_launch(void* const* d_in, const int* in_sizes, int n_in,
                              void* d_out, int out_size, void* d_ws, size_t ws_size,
                              hipStream_t stream)
{
    const int*   seq   = (const int*)  d_in[0];
    const float* embed = (const float*)d_in[1];
    const float* ffW1  = (const float*)d_in[2];
    const float* ffb1  = (const float*)d_in[3];
    const float* ffW2  = (const float*)d_in[4];
    const float* ffb2  = (const float*)d_in[5];
    const float* lng   = (const float*)d_in[6];
    const float* lnb   = (const float*)d_in[7];
    const float* kpW   = (const float*)d_in[8];
    const float* vpW   = (const float*)d_in[9];
    const float* qpW   = (const float*)d_in[10];
    const float* rpW   = (const float*)d_in[11];
    const float* rpb   = (const float*)d_in[12];
    const float* outW  = (const float*)d_in[13];
    const float* outb  = (const float*)d_in[14];
    float* out = (float*)d_out;

    float* knv  = (float*)d_ws;
    float* vthr = knv  + (size_t)64 * 1024 * 128;
    float* qbuf = vthr + (size_t)64 * 1024;

    static void* flags_ptr = nullptr;
    if (!flags_ptr) hipGetSymbolAddress(&flags_ptr, HIP_SYMBOL(g_flags));
    hipMemsetAsync(flags_ptr, 0, 2048 * sizeof(int), stream);

    fused_kernel<<<2112, 256, 0, stream>>>(seq, embed, ffW1, ffb1, ffW2, ffb2,
                                           lng, lnb, kpW, vpW, qpW,
                                           rpW, rpb, outW, outb,
                                           knv, vthr, qbuf, out);
}